// Round 1
// baseline (1194.365 us; speedup 1.0000x reference)
//
#include <hip/hip_runtime.h>
#include <math.h>

#define N_TOK 4096
#define REC 96

static constexpr float SCALE   = 0.17677669529663687f; // 32^-0.5
static constexpr float LAMBDA_ = 0.1f;

// ---------------------------------------------------------------------------
// Kernel 1: qkv projection. qkvT[h][n][96] = {q1*scale(16), q2*scale(16),
//           k1(16), k2(16), v(32)}.  grid 1024 x 128thr, 4 tokens per block.
// ---------------------------------------------------------------------------
__global__ __launch_bounds__(128) void qkv_kernel(
    const float* __restrict__ x, const float* __restrict__ w,
    float* __restrict__ qkvT)
{
    __shared__ float xs[128][5];          // +1 pad breaks bank conflicts
    const int t  = threadIdx.x;
    const int n0 = blockIdx.x * 4;

    #pragma unroll
    for (int i = 0; i < 4; ++i) {
        int n  = n0 + i;
        int nh = n >> 8, nw = (n >> 4) & 15, nz = n & 15;
        xs[t][i] = x[t * 32768 + nh * 2048 + nw * 64 + nz * 2];
    }
    __syncthreads();

    #pragma unroll
    for (int oi = 0; oi < 3; ++oi) {
        int o  = t + oi * 128;            // 0..383
        int hh = o / 96;
        int r  = o - hh * 96;
        const float4* wrow4 = (const float4*)(w + (size_t)o * 128);
        float a0 = 0.f, a1 = 0.f, a2 = 0.f, a3 = 0.f;
        #pragma unroll 8
        for (int c4 = 0; c4 < 32; ++c4) {
            float4 wv = wrow4[c4];
            int cb = c4 * 4;
            a0 += wv.x * xs[cb][0] + wv.y * xs[cb + 1][0] + wv.z * xs[cb + 2][0] + wv.w * xs[cb + 3][0];
            a1 += wv.x * xs[cb][1] + wv.y * xs[cb + 1][1] + wv.z * xs[cb + 2][1] + wv.w * xs[cb + 3][1];
            a2 += wv.x * xs[cb][2] + wv.y * xs[cb + 1][2] + wv.z * xs[cb + 2][2] + wv.w * xs[cb + 3][2];
            a3 += wv.x * xs[cb][3] + wv.y * xs[cb + 1][3] + wv.z * xs[cb + 2][3] + wv.w * xs[cb + 3][3];
        }
        float sc = (r < 32) ? SCALE : 1.0f;   // fold attention scale into q
        float* dst = qkvT + ((size_t)hh * N_TOK + n0) * REC + r;
        dst[0 * REC] = a0 * sc;
        dst[1 * REC] = a1 * sc;
        dst[2 * REC] = a2 * sc;
        dst[3 * REC] = a3 * sc;
    }
}

// ---------------------------------------------------------------------------
// Kernel 2: per-row softmax stats (m1,l1,m2,l2) for both branches.
// block = 256 thr = 64 queries x 4 key-chunks (1024 keys each).
// ---------------------------------------------------------------------------
__global__ __launch_bounds__(256) void stats_kernel(
    const float* __restrict__ qkvT, float* __restrict__ stats)
{
    const int h     = blockIdx.y;
    const int t     = threadIdx.x;
    const int qi    = t & 63;
    const int chunk = t >> 6;
    const int n     = blockIdx.x * 64 + qi;

    const float4* qp4 = (const float4*)(qkvT + ((size_t)h * N_TOK + n) * REC);
    float q1[16], q2[16];
    #pragma unroll
    for (int i = 0; i < 4; ++i) {
        float4 v = qp4[i];
        q1[4*i] = v.x; q1[4*i+1] = v.y; q1[4*i+2] = v.z; q1[4*i+3] = v.w;
    }
    #pragma unroll
    for (int i = 0; i < 4; ++i) {
        float4 v = qp4[4 + i];
        q2[4*i] = v.x; q2[4*i+1] = v.y; q2[4*i+2] = v.z; q2[4*i+3] = v.w;
    }

    float m1 = -1e30f, l1 = 0.f, m2 = -1e30f, l2 = 0.f;
    const float* kb = qkvT + (size_t)h * N_TOK * REC;
    const int j0 = chunk * 1024;
    for (int j = j0; j < j0 + 1024; ++j) {
        const float4* kp = (const float4*)(kb + (size_t)j * REC + 32);
        float s1 = 0.f, s2 = 0.f;
        #pragma unroll
        for (int i = 0; i < 4; ++i) {
            float4 kv = kp[i];
            s1 += q1[4*i]*kv.x + q1[4*i+1]*kv.y + q1[4*i+2]*kv.z + q1[4*i+3]*kv.w;
        }
        #pragma unroll
        for (int i = 0; i < 4; ++i) {
            float4 kv = kp[4 + i];
            s2 += q2[4*i]*kv.x + q2[4*i+1]*kv.y + q2[4*i+2]*kv.z + q2[4*i+3]*kv.w;
        }
        float mn1 = fmaxf(m1, s1);
        l1 = l1 * __expf(m1 - mn1) + __expf(s1 - mn1);
        m1 = mn1;
        float mn2 = fmaxf(m2, s2);
        l2 = l2 * __expf(m2 - mn2) + __expf(s2 - mn2);
        m2 = mn2;
    }

    __shared__ float4 red[256];
    red[t] = make_float4(m1, l1, m2, l2);
    __syncthreads();
    if (t < 64) {
        float4 a = red[t], b = red[t + 64], c = red[t + 128], d = red[t + 192];
        float m1f = fmaxf(fmaxf(a.x, b.x), fmaxf(c.x, d.x));
        float l1f = a.y * __expf(a.x - m1f) + b.y * __expf(b.x - m1f)
                  + c.y * __expf(c.x - m1f) + d.y * __expf(d.x - m1f);
        float m2f = fmaxf(fmaxf(a.z, b.z), fmaxf(c.z, d.z));
        float l2f = a.w * __expf(a.z - m2f) + b.w * __expf(b.z - m2f)
                  + c.w * __expf(c.z - m2f) + d.w * __expf(d.z - m2f);
        int nn = blockIdx.x * 64 + t;
        *(float4*)(stats + ((size_t)h * N_TOK + nn) * 4) =
            make_float4(m1f, l1f, m2f, l2f);
    }
}

// ---------------------------------------------------------------------------
// Kernel 3: output. weight per key collapses to one scalar since normalizers
// are precomputed: w = exp(s1-m1)/l1 - lambda*exp(s2-m2)/l2; out += w * v.
// ---------------------------------------------------------------------------
__global__ __launch_bounds__(256) void out_kernel(
    const float* __restrict__ qkvT, const float* __restrict__ stats,
    float* __restrict__ out)
{
    const int h     = blockIdx.y;
    const int t     = threadIdx.x;
    const int qi    = t & 63;
    const int chunk = t >> 6;
    const int n     = blockIdx.x * 64 + qi;

    const float4* qp4 = (const float4*)(qkvT + ((size_t)h * N_TOK + n) * REC);
    float q1[16], q2[16];
    #pragma unroll
    for (int i = 0; i < 4; ++i) {
        float4 v = qp4[i];
        q1[4*i] = v.x; q1[4*i+1] = v.y; q1[4*i+2] = v.z; q1[4*i+3] = v.w;
    }
    #pragma unroll
    for (int i = 0; i < 4; ++i) {
        float4 v = qp4[4 + i];
        q2[4*i] = v.x; q2[4*i+1] = v.y; q2[4*i+2] = v.z; q2[4*i+3] = v.w;
    }

    float4 st = *(const float4*)(stats + ((size_t)h * N_TOK + n) * 4);
    const float m1 = st.x, inv1 = 1.0f / st.y;
    const float m2 = st.z, inv2 = LAMBDA_ / st.w;

    float acc[32];
    #pragma unroll
    for (int d = 0; d < 32; ++d) acc[d] = 0.f;

    const float* kb = qkvT + (size_t)h * N_TOK * REC;
    const int j0 = chunk * 1024;
    for (int j = j0; j < j0 + 1024; ++j) {
        const float4* kp = (const float4*)(kb + (size_t)j * REC + 32);
        float s1 = 0.f, s2 = 0.f;
        #pragma unroll
        for (int i = 0; i < 4; ++i) {
            float4 kv = kp[i];
            s1 += q1[4*i]*kv.x + q1[4*i+1]*kv.y + q1[4*i+2]*kv.z + q1[4*i+3]*kv.w;
        }
        #pragma unroll
        for (int i = 0; i < 4; ++i) {
            float4 kv = kp[4 + i];
            s2 += q2[4*i]*kv.x + q2[4*i+1]*kv.y + q2[4*i+2]*kv.z + q2[4*i+3]*kv.w;
        }
        float wgt = __expf(s1 - m1) * inv1 - __expf(s2 - m2) * inv2;
        #pragma unroll
        for (int i = 0; i < 8; ++i) {
            float4 vv = kp[8 + i];     // v lives at record offset 64 floats
            acc[4*i]   += wgt * vv.x;
            acc[4*i+1] += wgt * vv.y;
            acc[4*i+2] += wgt * vv.z;
            acc[4*i+3] += wgt * vv.w;
        }
    }

    // reduce the 4 key-chunks per query in LDS (stride 33 avoids conflicts)
    __shared__ float red[64 * 33];
    if (chunk == 0) {
        #pragma unroll
        for (int d = 0; d < 32; ++d) red[qi * 33 + d] = acc[d];
    }
    __syncthreads();
    #pragma unroll
    for (int c = 1; c < 4; ++c) {
        if (chunk == c) {
            #pragma unroll
            for (int d = 0; d < 32; ++d) red[qi * 33 + d] += acc[d];
        }
        __syncthreads();
    }

    float* ob = out + ((size_t)h * N_TOK + blockIdx.x * 64) * 32;
    for (int i = t; i < 64 * 32; i += 256) {
        ob[i] = red[(i >> 5) * 33 + (i & 31)];
    }
}

extern "C" void kernel_launch(void* const* d_in, const int* in_sizes, int n_in,
                              void* d_out, int out_size, void* d_ws, size_t ws_size,
                              hipStream_t stream) {
    const float* x = (const float*)d_in[0];   // (1,128,32,32,32)
    const float* w = (const float*)d_in[1];   // (384,128)
    float* out   = (float*)d_out;             // (1,128,16,16,16) == [h][n][d] flat
    float* qkvT  = (float*)d_ws;                              // 4*4096*96 floats
    float* stats = qkvT + (size_t)4 * N_TOK * REC;            // 4*4096*4 floats

    qkv_kernel<<<1024, 128, 0, stream>>>(x, w, qkvT);
    dim3 grid(64, 4);
    stats_kernel<<<grid, 256, 0, stream>>>(qkvT, stats);
    out_kernel<<<grid, 256, 0, stream>>>(qkvT, stats, out);
}

// Round 2
// 1147.354 us; speedup vs baseline: 1.0410x; 1.0410x over previous
//
#include <hip/hip_runtime.h>
#include <math.h>

#define N_TOK   4096
#define NH      4
#define SPLITS  16
#define KPS     (N_TOK / SPLITS)   // 256 keys per split
#define TILE    64                 // keys per LDS tile
#define NTILES  (KPS / TILE)       // 4
#define ROWS    (NH * N_TOK)       // 16384

static constexpr float SCALE   = 0.17677669529663687f; // 32^-0.5
static constexpr float LAMBDA_ = 0.1f;

__device__ __forceinline__ void async_copy16(const float* g, float* l) {
    __builtin_amdgcn_global_load_lds(
        (const __attribute__((address_space(1))) void*)g,
        (__attribute__((address_space(3))) void*)l, 16, 0, 0);
}

// ---------------------------------------------------------------------------
// Kernel 1: qkv projection.
//   qT [h][n][32] = {q1*scale(16), q2*scale(16)}
//   kvT[h][n][64] = {k1(16), k2(16), v(32)}
// grid 1024 x 128 thr, 4 tokens per block.  (verified correct in R1 form)
// ---------------------------------------------------------------------------
__global__ __launch_bounds__(128) void qkv_kernel(
    const float* __restrict__ x, const float* __restrict__ w,
    float* __restrict__ qT, float* __restrict__ kvT)
{
    __shared__ float xs[128][5];          // +1 pad breaks bank conflicts
    const int t  = threadIdx.x;
    const int n0 = blockIdx.x * 4;

    #pragma unroll
    for (int i = 0; i < 4; ++i) {
        int n  = n0 + i;
        int nh = n >> 8, nw = (n >> 4) & 15, nz = n & 15;
        xs[t][i] = x[t * 32768 + nh * 2048 + nw * 64 + nz * 2];
    }
    __syncthreads();

    #pragma unroll
    for (int oi = 0; oi < 3; ++oi) {
        int o  = t + oi * 128;            // 0..383
        int hh = o / 96;
        int r  = o - hh * 96;
        const float4* wrow4 = (const float4*)(w + (size_t)o * 128);
        float a0 = 0.f, a1 = 0.f, a2 = 0.f, a3 = 0.f;
        #pragma unroll 8
        for (int c4 = 0; c4 < 32; ++c4) {
            float4 wv = wrow4[c4];
            int cb = c4 * 4;
            a0 += wv.x * xs[cb][0] + wv.y * xs[cb + 1][0] + wv.z * xs[cb + 2][0] + wv.w * xs[cb + 3][0];
            a1 += wv.x * xs[cb][1] + wv.y * xs[cb + 1][1] + wv.z * xs[cb + 2][1] + wv.w * xs[cb + 3][1];
            a2 += wv.x * xs[cb][2] + wv.y * xs[cb + 1][2] + wv.z * xs[cb + 2][2] + wv.w * xs[cb + 3][2];
            a3 += wv.x * xs[cb][3] + wv.y * xs[cb + 1][3] + wv.z * xs[cb + 2][3] + wv.w * xs[cb + 3][3];
        }
        if (r < 32) {
            float* dst = qT + ((size_t)hh * N_TOK + n0) * 32 + r;
            dst[0]  = a0 * SCALE;
            dst[32] = a1 * SCALE;
            dst[64] = a2 * SCALE;
            dst[96] = a3 * SCALE;
        } else {
            float* dst = kvT + ((size_t)hh * N_TOK + n0) * 64 + (r - 32);
            dst[0]   = a0;
            dst[64]  = a1;
            dst[128] = a2;
            dst[192] = a3;
        }
    }
}

// ---------------------------------------------------------------------------
// Kernel 2: fused flash diff-attention, fixed-max softmax (scores bounded ~±5).
// grid (16 qblocks, 4 heads, 16 ksplits), 256 thr; 1 query-row per thread,
// 256 keys per block staged through double-buffered LDS via global_load_lds.
// Partials merged with fp32 atomicAdd into wsAcc[row][68].
// ---------------------------------------------------------------------------
__global__ __launch_bounds__(256, 4) void flash_kernel(
    const float* __restrict__ qT, const float* __restrict__ kvT,
    float* __restrict__ wsAcc)
{
    __shared__ float kv[2][TILE * 64];    // 2 x 16 KB
    const int t   = threadIdx.x;
    const int h   = blockIdx.y;
    const int n   = blockIdx.x * 256 + t;
    const int ks  = blockIdx.z;
    const int row = h * N_TOK + n;

    // per-row query (scale pre-folded)
    float q1[16], q2[16];
    {
        const float4* qp = (const float4*)(qT + (size_t)row * 32);
        #pragma unroll
        for (int i = 0; i < 4; ++i) {
            float4 v = qp[i];
            q1[4*i] = v.x; q1[4*i+1] = v.y; q1[4*i+2] = v.z; q1[4*i+3] = v.w;
        }
        #pragma unroll
        for (int i = 0; i < 4; ++i) {
            float4 v = qp[4 + i];
            q2[4*i] = v.x; q2[4*i+1] = v.y; q2[4*i+2] = v.z; q2[4*i+3] = v.w;
        }
    }

    float l1 = 0.f, l2 = 0.f;
    float acc1[32], acc2[32];
    #pragma unroll
    for (int d = 0; d < 32; ++d) { acc1[d] = 0.f; acc2[d] = 0.f; }

    const float* gbase = kvT + ((size_t)h * N_TOK + ks * KPS) * 64;
    const int wslot = t & ~63;            // wave-uniform LDS base slot

    // prefetch tile 0 into buf 0
    #pragma unroll
    for (int i = 0; i < 4; ++i)
        async_copy16(gbase + (size_t)(t + 256 * i) * 4,
                     &kv[0][(wslot + 256 * i) * 4]);

    int cur = 0;
    for (int tile = 0; tile < NTILES; ++tile) {
        __syncthreads();                  // drains loads of kv[cur]
        if (tile + 1 < NTILES) {
            const float* gn = gbase + (size_t)(tile + 1) * TILE * 64;
            #pragma unroll
            for (int i = 0; i < 4; ++i)
                async_copy16(gn + (size_t)(t + 256 * i) * 4,
                             &kv[cur ^ 1][(wslot + 256 * i) * 4]);
        }

        const float* buf = kv[cur];
        #pragma unroll 4
        for (int kk = 0; kk < TILE; ++kk) {
            const float4* kp = (const float4*)(buf + kk * 64);
            float s1 = 0.f, s2 = 0.f;
            #pragma unroll
            for (int i = 0; i < 4; ++i) {
                float4 kvv = kp[i];
                s1 += q1[4*i]*kvv.x + q1[4*i+1]*kvv.y + q1[4*i+2]*kvv.z + q1[4*i+3]*kvv.w;
            }
            #pragma unroll
            for (int i = 0; i < 4; ++i) {
                float4 kvv = kp[4 + i];
                s2 += q2[4*i]*kvv.x + q2[4*i+1]*kvv.y + q2[4*i+2]*kvv.z + q2[4*i+3]*kvv.w;
            }
            float e1 = __expf(s1), e2 = __expf(s2);
            l1 += e1; l2 += e2;
            #pragma unroll
            for (int i = 0; i < 8; ++i) {
                float4 vv = kp[8 + i];
                acc1[4*i]   += e1 * vv.x;  acc2[4*i]   += e2 * vv.x;
                acc1[4*i+1] += e1 * vv.y;  acc2[4*i+1] += e2 * vv.y;
                acc1[4*i+2] += e1 * vv.z;  acc2[4*i+2] += e2 * vv.z;
                acc1[4*i+3] += e1 * vv.w;  acc2[4*i+3] += e2 * vv.w;
            }
        }
        cur ^= 1;
    }

    float* dst = wsAcc + (size_t)row * 68;
    #pragma unroll
    for (int d = 0; d < 32; ++d) {
        atomicAdd(dst + d,      acc1[d]);
        atomicAdd(dst + 32 + d, acc2[d]);
    }
    atomicAdd(dst + 64, l1);
    atomicAdd(dst + 65, l2);
}

// ---------------------------------------------------------------------------
// Kernel 3: finalize  out[row][d] = acc1/l1 - lambda*acc2/l2
// ---------------------------------------------------------------------------
__global__ __launch_bounds__(256) void finalize_kernel(
    const float* __restrict__ wsAcc, float* __restrict__ out)
{
    int idx = blockIdx.x * 256 + threadIdx.x;     // 524288 total
    int row = idx >> 5, d = idx & 31;
    const float* p = wsAcc + (size_t)row * 68;
    float inv1 = 1.0f / p[64];
    float inv2 = LAMBDA_ / p[65];
    out[idx] = p[d] * inv1 - p[32 + d] * inv2;
}

extern "C" void kernel_launch(void* const* d_in, const int* in_sizes, int n_in,
                              void* d_out, int out_size, void* d_ws, size_t ws_size,
                              hipStream_t stream) {
    const float* x = (const float*)d_in[0];   // (1,128,32,32,32)
    const float* w = (const float*)d_in[1];   // (384,128)
    float* out = (float*)d_out;               // [h][n][32] flat (verified R1)

    float* qT    = (float*)d_ws;                        // 4*4096*32 = 2.10 MB
    float* kvT   = qT  + (size_t)NH * N_TOK * 32;       // 4*4096*64 = 4.19 MB
    float* wsAcc = kvT + (size_t)NH * N_TOK * 64;       // 16384*68  = 4.46 MB

    hipMemsetAsync(wsAcc, 0, (size_t)ROWS * 68 * sizeof(float), stream);
    qkv_kernel<<<1024, 128, 0, stream>>>(x, w, qT, kvT);
    flash_kernel<<<dim3(16, NH, SPLITS), 256, 0, stream>>>(qT, kvT, wsAcc);
    finalize_kernel<<<(ROWS * 32) / 256, 256, 0, stream>>>(wsAcc, out);
}

// Round 3
// 381.247 us; speedup vs baseline: 3.1328x; 3.0095x over previous
//
#include <hip/hip_runtime.h>
#include <math.h>

#define N_TOK   4096
#define NH      4
#define TILE    64                 // keys per staged LDS tile
#define NTILES  (N_TOK / TILE)     // 64
#define RSTRIDE 67                 // 64q x 67 reduction stride (bank-friendly)

static constexpr float SCALE   = 0.17677669529663687f; // 32^-0.5
static constexpr float LAMBDA_ = 0.1f;

__device__ __forceinline__ void async_copy16(const float* g, float* l) {
    __builtin_amdgcn_global_load_lds(
        (const __attribute__((address_space(1))) void*)g,
        (__attribute__((address_space(3))) void*)l, 16, 0, 0);
}

// ---------------------------------------------------------------------------
// Kernel 1: qkv projection.
//   qT [h][n][32] = {q1*scale(16), q2*scale(16)}
//   kvT[h][n][64] = {k1(16), k2(16), v(32)}
// grid 1024 x 128 thr, 4 tokens per block. (verified correct R1/R2)
// ---------------------------------------------------------------------------
__global__ __launch_bounds__(128) void qkv_kernel(
    const float* __restrict__ x, const float* __restrict__ w,
    float* __restrict__ qT, float* __restrict__ kvT)
{
    __shared__ float xs[128][5];
    const int t  = threadIdx.x;
    const int n0 = blockIdx.x * 4;

    #pragma unroll
    for (int i = 0; i < 4; ++i) {
        int n  = n0 + i;
        int nh = n >> 8, nw = (n >> 4) & 15, nz = n & 15;
        xs[t][i] = x[t * 32768 + nh * 2048 + nw * 64 + nz * 2];
    }
    __syncthreads();

    #pragma unroll
    for (int oi = 0; oi < 3; ++oi) {
        int o  = t + oi * 128;            // 0..383
        int hh = o / 96;
        int r  = o - hh * 96;
        const float4* wrow4 = (const float4*)(w + (size_t)o * 128);
        float a0 = 0.f, a1 = 0.f, a2 = 0.f, a3 = 0.f;
        #pragma unroll 8
        for (int c4 = 0; c4 < 32; ++c4) {
            float4 wv = wrow4[c4];
            int cb = c4 * 4;
            a0 += wv.x * xs[cb][0] + wv.y * xs[cb + 1][0] + wv.z * xs[cb + 2][0] + wv.w * xs[cb + 3][0];
            a1 += wv.x * xs[cb][1] + wv.y * xs[cb + 1][1] + wv.z * xs[cb + 2][1] + wv.w * xs[cb + 3][1];
            a2 += wv.x * xs[cb][2] + wv.y * xs[cb + 1][2] + wv.z * xs[cb + 2][2] + wv.w * xs[cb + 3][2];
            a3 += wv.x * xs[cb][3] + wv.y * xs[cb + 1][3] + wv.z * xs[cb + 2][3] + wv.w * xs[cb + 3][3];
        }
        if (r < 32) {
            float* dst = qT + ((size_t)hh * N_TOK + n0) * 32 + r;
            dst[0]  = a0 * SCALE;
            dst[32] = a1 * SCALE;
            dst[64] = a2 * SCALE;
            dst[96] = a3 * SCALE;
        } else {
            float* dst = kvT + ((size_t)hh * N_TOK + n0) * 64 + (r - 32);
            dst[0]   = a0;
            dst[64]  = a1;
            dst[128] = a2;
            dst[192] = a3;
        }
    }
}

// ---------------------------------------------------------------------------
// Kernel 2: fused flash diff-attention. One block = 64 query-rows x ALL keys.
// 512 thr = 8 waves; thread owns query qi=t&63; wave w handles tile-keys
// {8*kk + w}, so every wave shares one staged K/V tile (no per-wave streams,
// no global atomics). Split-K merge via LDS ds_add_f32; finalize fused.
// ---------------------------------------------------------------------------
__global__ __launch_bounds__(512, 2) void flash_kernel(
    const float* __restrict__ qT, const float* __restrict__ kvT,
    float* __restrict__ out)
{
    __shared__ float kv[2][TILE * 64];      // 2 x 16 KB
    __shared__ float red[64 * RSTRIDE];     // 17.2 KB
    const int t       = threadIdx.x;
    const int qi      = t & 63;
    const int w       = t >> 6;             // 0..7
    const int rowbase = blockIdx.x * 64;
    const int row     = rowbase + qi;
    const int h       = row >> 12;

    for (int i = t; i < 64 * RSTRIDE; i += 512) red[i] = 0.f;

    float q1[16], q2[16];
    {
        const float4* qp = (const float4*)(qT + (size_t)row * 32);
        #pragma unroll
        for (int i = 0; i < 4; ++i) {
            float4 v = qp[i];
            q1[4*i] = v.x; q1[4*i+1] = v.y; q1[4*i+2] = v.z; q1[4*i+3] = v.w;
        }
        #pragma unroll
        for (int i = 0; i < 4; ++i) {
            float4 v = qp[4 + i];
            q2[4*i] = v.x; q2[4*i+1] = v.y; q2[4*i+2] = v.z; q2[4*i+3] = v.w;
        }
    }

    float l1 = 0.f, l2 = 0.f;
    float acc1[32], acc2[32];
    #pragma unroll
    for (int d = 0; d < 32; ++d) { acc1[d] = 0.f; acc2[d] = 0.f; }

    const float* gbase = kvT + (size_t)h * N_TOK * 64;

    // prefetch tile 0 (each thread copies float4 #t and #(t+512); LDS dest is
    // wave-base + lane*16 as required by global_load_lds)
    async_copy16(gbase + (size_t)t * 4,         &kv[0][t * 4]);
    async_copy16(gbase + (size_t)(t + 512) * 4, &kv[0][(t + 512) * 4]);

    int cur = 0;
    for (int tile = 0; tile < NTILES; ++tile) {
        __syncthreads();                    // drains prefetch of kv[cur]
        if (tile + 1 < NTILES) {
            const float* gn = gbase + (size_t)(tile + 1) * TILE * 64;
            async_copy16(gn + (size_t)t * 4,         &kv[cur ^ 1][t * 4]);
            async_copy16(gn + (size_t)(t + 512) * 4, &kv[cur ^ 1][(t + 512) * 4]);
        }

        const float* buf = kv[cur];
        #pragma unroll
        for (int kk = 0; kk < 8; ++kk) {
            const float4* kp = (const float4*)(buf + (kk * 8 + w) * 64);
            float s1 = 0.f, s2 = 0.f;
            #pragma unroll
            for (int i = 0; i < 4; ++i) {
                float4 kvv = kp[i];
                s1 += q1[4*i]*kvv.x + q1[4*i+1]*kvv.y + q1[4*i+2]*kvv.z + q1[4*i+3]*kvv.w;
            }
            #pragma unroll
            for (int i = 0; i < 4; ++i) {
                float4 kvv = kp[4 + i];
                s2 += q2[4*i]*kvv.x + q2[4*i+1]*kvv.y + q2[4*i+2]*kvv.z + q2[4*i+3]*kvv.w;
            }
            float e1 = __expf(s1), e2 = __expf(s2);
            l1 += e1; l2 += e2;
            #pragma unroll
            for (int i = 0; i < 8; ++i) {
                float4 vv = kp[8 + i];
                acc1[4*i]   += e1 * vv.x;  acc2[4*i]   += e2 * vv.x;
                acc1[4*i+1] += e1 * vv.y;  acc2[4*i+1] += e2 * vv.y;
                acc1[4*i+2] += e1 * vv.z;  acc2[4*i+2] += e2 * vv.z;
                acc1[4*i+3] += e1 * vv.w;  acc2[4*i+3] += e2 * vv.w;
            }
        }
        cur ^= 1;
    }

    // merge the 8 wave-partials per query in LDS (2-way bank alias = free)
    __syncthreads();
    float* rq = red + qi * RSTRIDE;
    #pragma unroll
    for (int d = 0; d < 32; ++d) atomicAdd(rq + d,      acc1[d]);
    #pragma unroll
    for (int d = 0; d < 32; ++d) atomicAdd(rq + 32 + d, acc2[d]);
    atomicAdd(rq + 64, l1);
    atomicAdd(rq + 65, l2);
    __syncthreads();

    // finalize: out = acc1/l1 - lambda*acc2/l2, coalesced store
    for (int i = t; i < 64 * 32; i += 512) {
        int q = i >> 5, d = i & 31;
        const float* r = red + q * RSTRIDE;
        float inv1 = 1.0f / r[64];
        float inv2 = LAMBDA_ / r[65];
        out[(size_t)rowbase * 32 + i] = r[d] * inv1 - r[32 + d] * inv2;
    }
}

extern "C" void kernel_launch(void* const* d_in, const int* in_sizes, int n_in,
                              void* d_out, int out_size, void* d_ws, size_t ws_size,
                              hipStream_t stream) {
    const float* x = (const float*)d_in[0];   // (1,128,32,32,32)
    const float* w = (const float*)d_in[1];   // (384,128)
    float* out = (float*)d_out;               // [h][n][32] flat

    float* qT  = (float*)d_ws;                        // 4*4096*32 = 2.10 MB
    float* kvT = qT + (size_t)NH * N_TOK * 32;        // 4*4096*64 = 4.19 MB

    qkv_kernel<<<1024, 128, 0, stream>>>(x, w, qT, kvT);
    flash_kernel<<<256, 512, 0, stream>>>(qT, kvT, out);
}

// Round 4
// 248.000 us; speedup vs baseline: 4.8160x; 1.5373x over previous
//
#include <hip/hip_runtime.h>
#include <math.h>

#define N_TOK 4096
#define NH    4

typedef __attribute__((ext_vector_type(8))) short bf16x8;
typedef __attribute__((ext_vector_type(4))) float f32x4;

static constexpr float SCALE   = 0.17677669529663687f; // 32^-0.5
static constexpr float LAMBDA_ = 0.1f;

__device__ __forceinline__ unsigned short bf_rne(float f) {
    unsigned u = __float_as_uint(f);
    u += 0x7FFF + ((u >> 16) & 1);
    return (unsigned short)(u >> 16);
}

// ---------------------------------------------------------------------------
// Kernel 1: qkv projection + operand packing.
//  qA[h][n][64] bf16: {q1hi(16) q1lo(16) q2hi(16) q2lo(16)}  (scale folded)
//  kB[h][n][64] bf16: {k1hi(16) k1lo(16) k2hi(16) k2lo(16)}
//  vT[h][32][4096] bf16 (transposed, RNE)
// hi = bf16-truncate, lo = bf16(x - hi): hi+lo reconstructs to ~2^-16 rel.
// ---------------------------------------------------------------------------
__global__ __launch_bounds__(128) void qkv_kernel(
    const float* __restrict__ x, const float* __restrict__ w,
    unsigned short* __restrict__ qA, unsigned short* __restrict__ kB,
    unsigned short* __restrict__ vT)
{
    __shared__ float xs[128][5];
    const int t  = threadIdx.x;
    const int n0 = blockIdx.x * 4;

    #pragma unroll
    for (int i = 0; i < 4; ++i) {
        int n  = n0 + i;
        int nh = n >> 8, nw = (n >> 4) & 15, nz = n & 15;
        xs[t][i] = x[t * 32768 + nh * 2048 + nw * 64 + nz * 2];
    }
    __syncthreads();

    #pragma unroll
    for (int oi = 0; oi < 3; ++oi) {
        int o  = t + oi * 128;            // 0..383
        int hh = o / 96;
        int r  = o - hh * 96;
        const float4* wrow4 = (const float4*)(w + (size_t)o * 128);
        float acc[4] = {0.f, 0.f, 0.f, 0.f};
        #pragma unroll 8
        for (int c4 = 0; c4 < 32; ++c4) {
            float4 wv = wrow4[c4];
            int cb = c4 * 4;
            #pragma unroll
            for (int i = 0; i < 4; ++i)
                acc[i] += wv.x * xs[cb][i] + wv.y * xs[cb + 1][i]
                        + wv.z * xs[cb + 2][i] + wv.w * xs[cb + 3][i];
        }
        if (r < 64) {                     // q (r<32) or k (32..63): hi/lo split
            unsigned short* dst = (r < 32) ? qA : kB;
            int rr   = (r < 32) ? r : (r - 32);
            int part = rr >> 4;           // 0: half1, 1: half2
            int d    = rr & 15;
            float sc = (r < 32) ? SCALE : 1.0f;
            #pragma unroll
            for (int i = 0; i < 4; ++i) {
                float f = acc[i] * sc;
                unsigned u  = __float_as_uint(f);
                unsigned hb = u & 0xFFFF0000u;
                float lo = f - __uint_as_float(hb);
                size_t base = ((size_t)hh * N_TOK + n0 + i) * 64 + part * 32 + d;
                dst[base]      = (unsigned short)(u >> 16);
                dst[base + 16] = (unsigned short)(__float_as_uint(lo) >> 16);
            }
        } else {                          // v -> transposed bf16 RNE
            int d = r - 64;
            #pragma unroll
            for (int i = 0; i < 4; ++i)
                vT[((size_t)hh * 32 + d) * N_TOK + n0 + i] = bf_rne(acc[i]);
        }
    }
}

// ---------------------------------------------------------------------------
// Kernel 2: MFMA flash diff-attention.
// block = 256 thr = 4 waves; block owns one 16-row qtile; wave w owns keys
// [w*1024,(w+1)*1024). Per 32-key group: S via 16x16x32 bf16 MFMA (split-hi/lo,
// 2 MFMA/branch/16keys), exp, P->LDS (C-layout), readback (A-layout) + rowsum,
// PV MFMA vs bf16 V. No __syncthreads in K-loop (per-wave LDS scratch).
// Merge 4 wave-partials via LDS atomics; finalize by wave 0.
// MFMA layouts (guide-verified): A[m=lane&15][k=quad*8+j]; B[n=lane&15][k=quad*8+j];
// C/D col=lane&15, row=quad*4+reg.
// ---------------------------------------------------------------------------
__global__ __launch_bounds__(256, 4) void flash_kernel(
    const unsigned short* __restrict__ qA, const unsigned short* __restrict__ kB,
    const unsigned short* __restrict__ vT, float* __restrict__ out)
{
    __shared__ float Pb[4][2][16 * 36];   // per-wave, per-branch P scratch (18 KB)
    __shared__ float Obuf[2][16][32];     // merge: 2 branches x 16 rows x 32 cols
    __shared__ float lbuf[2][16];

    const int t    = threadIdx.x;
    const int w    = t >> 6;
    const int lane = t & 63;
    const int m    = lane & 15;
    const int quad = lane >> 4;
    const int h     = blockIdx.x >> 8;
    const int qbase = (blockIdx.x & 255) * 16;

    for (int i = t; i < 1024; i += 256) ((float*)Obuf)[i] = 0.f;
    if (t < 32) ((float*)lbuf)[t] = 0.f;
    __syncthreads();

    // A-operand fragments for Q (once per wave): A1=[q1hi|q1lo], A2=[q2hi|q2lo]
    const size_t tok = (size_t)(h * N_TOK + qbase + m);
    bf16x8 A1 = *(const bf16x8*)(qA + tok * 64 + quad * 8);
    bf16x8 A2 = *(const bf16x8*)(qA + tok * 64 + 32 + quad * 8);

    f32x4 O1a = {0,0,0,0}, O1b = {0,0,0,0}, O2a = {0,0,0,0}, O2b = {0,0,0,0};
    float l1 = 0.f, l2 = 0.f;
    float* P1 = &Pb[w][0][0];
    float* P2 = &Pb[w][1][0];

    const unsigned short* kBh = kB + (size_t)h * N_TOK * 64;
    const unsigned short* vTh = vT + (size_t)h * 32 * N_TOK;
    const int  dsel   = (quad & 1) * 8;
    const bool loquad = (quad < 2);
    const bf16x8 zz = {0,0,0,0,0,0,0,0};

    for (int g = 0; g < 32; ++g) {
        const int kb0 = w * 1024 + g * 32;

        #pragma unroll
        for (int kt = 0; kt < 2; ++kt) {
            const unsigned short* kp = kBh + (size_t)(kb0 + kt * 16 + m) * 64;
            bf16x8 b1m = *(const bf16x8*)(kp + dsel);          // [k1hi|k1hi]
            bf16x8 b1l = *(const bf16x8*)(kp + 16 + dsel);
            bf16x8 b2m = *(const bf16x8*)(kp + 32 + dsel);
            bf16x8 b2l = *(const bf16x8*)(kp + 48 + dsel);
            bf16x8 b1c = loquad ? b1l : zz;                    // [k1lo|0]
            bf16x8 b2c = loquad ? b2l : zz;

            f32x4 s1 = {0,0,0,0};
            s1 = __builtin_amdgcn_mfma_f32_16x16x32_bf16(A1, b1m, s1, 0, 0, 0);
            s1 = __builtin_amdgcn_mfma_f32_16x16x32_bf16(A1, b1c, s1, 0, 0, 0);
            f32x4 s2 = {0,0,0,0};
            s2 = __builtin_amdgcn_mfma_f32_16x16x32_bf16(A2, b2m, s2, 0, 0, 0);
            s2 = __builtin_amdgcn_mfma_f32_16x16x32_bf16(A2, b2c, s2, 0, 0, 0);

            #pragma unroll
            for (int i = 0; i < 4; ++i) {                      // C-layout stash
                int r = quad * 4 + i;
                P1[r * 36 + kt * 16 + m] = __expf(s1[i]);
                P2[r * 36 + kt * 16 + m] = __expf(s2[i]);
            }
        }

        // readback in A-layout (same wave: LDS pipe is in-order, no barrier)
        float4 pa = *(const float4*)(P1 + m * 36 + quad * 8);
        float4 pb = *(const float4*)(P1 + m * 36 + quad * 8 + 4);
        float4 pc = *(const float4*)(P2 + m * 36 + quad * 8);
        float4 pd = *(const float4*)(P2 + m * 36 + quad * 8 + 4);
        l1 += pa.x + pa.y + pa.z + pa.w + pb.x + pb.y + pb.z + pb.w;
        l2 += pc.x + pc.y + pc.z + pc.w + pd.x + pd.y + pd.z + pd.w;
        bf16x8 aP1, aP2;
        aP1[0] = (short)(__float_as_uint(pa.x) >> 16);
        aP1[1] = (short)(__float_as_uint(pa.y) >> 16);
        aP1[2] = (short)(__float_as_uint(pa.z) >> 16);
        aP1[3] = (short)(__float_as_uint(pa.w) >> 16);
        aP1[4] = (short)(__float_as_uint(pb.x) >> 16);
        aP1[5] = (short)(__float_as_uint(pb.y) >> 16);
        aP1[6] = (short)(__float_as_uint(pb.z) >> 16);
        aP1[7] = (short)(__float_as_uint(pb.w) >> 16);
        aP2[0] = (short)(__float_as_uint(pc.x) >> 16);
        aP2[1] = (short)(__float_as_uint(pc.y) >> 16);
        aP2[2] = (short)(__float_as_uint(pc.z) >> 16);
        aP2[3] = (short)(__float_as_uint(pc.w) >> 16);
        aP2[4] = (short)(__float_as_uint(pd.x) >> 16);
        aP2[5] = (short)(__float_as_uint(pd.y) >> 16);
        aP2[6] = (short)(__float_as_uint(pd.z) >> 16);
        aP2[7] = (short)(__float_as_uint(pd.w) >> 16);

        bf16x8 Vb0 = *(const bf16x8*)(vTh + (size_t)m        * N_TOK + kb0 + quad * 8);
        bf16x8 Vb1 = *(const bf16x8*)(vTh + (size_t)(16 + m) * N_TOK + kb0 + quad * 8);

        O1a = __builtin_amdgcn_mfma_f32_16x16x32_bf16(aP1, Vb0, O1a, 0, 0, 0);
        O1b = __builtin_amdgcn_mfma_f32_16x16x32_bf16(aP1, Vb1, O1b, 0, 0, 0);
        O2a = __builtin_amdgcn_mfma_f32_16x16x32_bf16(aP2, Vb0, O2a, 0, 0, 0);
        O2b = __builtin_amdgcn_mfma_f32_16x16x32_bf16(aP2, Vb1, O2b, 0, 0, 0);
    }

    // l: sum the 4 quad-partials per row within the wave
    l1 += __shfl_xor(l1, 16, 64); l1 += __shfl_xor(l1, 32, 64);
    l2 += __shfl_xor(l2, 16, 64); l2 += __shfl_xor(l2, 32, 64);
    if (lane < 16) {
        atomicAdd(&lbuf[0][m], l1);
        atomicAdd(&lbuf[1][m], l2);
    }
    #pragma unroll
    for (int i = 0; i < 4; ++i) {
        int r = quad * 4 + i;
        atomicAdd(&Obuf[0][r][m],      O1a[i]);
        atomicAdd(&Obuf[0][r][16 + m], O1b[i]);
        atomicAdd(&Obuf[1][r][m],      O2a[i]);
        atomicAdd(&Obuf[1][r][16 + m], O2b[i]);
    }
    __syncthreads();

    if (w == 0) {
        #pragma unroll
        for (int i = 0; i < 4; ++i) {
            int r = quad * 4 + i;
            float il1 = 1.0f   / lbuf[0][r];
            float il2 = LAMBDA_ / lbuf[1][r];
            float* op = out + ((size_t)(h * N_TOK + qbase + r)) * 32;
            op[m]      = Obuf[0][r][m]      * il1 - Obuf[1][r][m]      * il2;
            op[16 + m] = Obuf[0][r][16 + m] * il1 - Obuf[1][r][16 + m] * il2;
        }
    }
}

extern "C" void kernel_launch(void* const* d_in, const int* in_sizes, int n_in,
                              void* d_out, int out_size, void* d_ws, size_t ws_size,
                              hipStream_t stream) {
    const float* x = (const float*)d_in[0];   // (1,128,32,32,32)
    const float* w = (const float*)d_in[1];   // (384,128)
    float* out = (float*)d_out;               // [h][n][32] flat (verified R1)

    unsigned short* qA = (unsigned short*)d_ws;               // 4*4096*64*2B = 2 MB
    unsigned short* kB = qA + (size_t)NH * N_TOK * 64;        // 2 MB
    unsigned short* vT = kB + (size_t)NH * N_TOK * 64;        // 4*32*4096*2B = 1 MB

    qkv_kernel<<<1024, 128, 0, stream>>>(x, w, qA, kB, vT);
    flash_kernel<<<1024, 256, 0, stream>>>(qA, kB, vT, out);
}

// Round 5
// 215.527 us; speedup vs baseline: 5.5416x; 1.1507x over previous
//
#include <hip/hip_runtime.h>
#include <math.h>

#define N_TOK 4096
#define NH    4

typedef __attribute__((ext_vector_type(8))) short bf16x8;
typedef __attribute__((ext_vector_type(4))) short bf16x4;
typedef __attribute__((ext_vector_type(4))) float f32x4;

static constexpr float SCALE   = 0.17677669529663687f; // 32^-0.5
static constexpr float LAMBDA_ = 0.1f;

__device__ __forceinline__ unsigned short bf_rne(float f) {
    unsigned u = __float_as_uint(f);
    u += 0x7FFF + ((u >> 16) & 1);
    return (unsigned short)(u >> 16);
}

// ---------------------------------------------------------------------------
// Kernel 1: qkv projection + operand packing.
//  qA[h][n][64] bf16: {q1hi(16) q1lo(16) q2hi(16) q2lo(16)}  (scale folded)
//  kB[h][n][64] bf16: {k1hi(16) k1lo(16) k2hi(16) k2lo(16)}
//  vT[h][32][4096] bf16 (transposed, RNE)
// x staged transposed (xst[token][channel]) so reads are broadcast b128;
// x read hoisted over the 3 output rows (1 b128 : 12 FMA).
// ---------------------------------------------------------------------------
__global__ __launch_bounds__(128) void qkv_kernel(
    const float* __restrict__ x, const float* __restrict__ w,
    unsigned short* __restrict__ qA, unsigned short* __restrict__ kB,
    unsigned short* __restrict__ vT)
{
    __shared__ float xst[4][128];         // [token][channel]
    const int t  = threadIdx.x;
    const int n0 = blockIdx.x * 4;

    #pragma unroll
    for (int i = 0; i < 4; ++i) {
        int n  = n0 + i;
        int nh = n >> 8, nw = (n >> 4) & 15, nz = n & 15;
        xst[i][t] = x[t * 32768 + nh * 2048 + nw * 64 + nz * 2];
    }
    __syncthreads();

    float acc[3][4];
    #pragma unroll
    for (int oi = 0; oi < 3; ++oi)
        #pragma unroll
        for (int i = 0; i < 4; ++i) acc[oi][i] = 0.f;

    const float4* wr0 = (const float4*)(w + (size_t)(t)       * 128);
    const float4* wr1 = (const float4*)(w + (size_t)(t + 128) * 128);
    const float4* wr2 = (const float4*)(w + (size_t)(t + 256) * 128);

    #pragma unroll 4
    for (int c4 = 0; c4 < 32; ++c4) {
        float4 xv[4];
        #pragma unroll
        for (int i = 0; i < 4; ++i) xv[i] = *(const float4*)&xst[i][c4 * 4];
        float4 wv0 = wr0[c4], wv1 = wr1[c4], wv2 = wr2[c4];
        #pragma unroll
        for (int i = 0; i < 4; ++i) {
            acc[0][i] += wv0.x*xv[i].x + wv0.y*xv[i].y + wv0.z*xv[i].z + wv0.w*xv[i].w;
            acc[1][i] += wv1.x*xv[i].x + wv1.y*xv[i].y + wv1.z*xv[i].z + wv1.w*xv[i].w;
            acc[2][i] += wv2.x*xv[i].x + wv2.y*xv[i].y + wv2.z*xv[i].z + wv2.w*xv[i].w;
        }
    }

    #pragma unroll
    for (int oi = 0; oi < 3; ++oi) {
        int o  = t + oi * 128;            // 0..383
        int hh = o / 96;
        int r  = o - hh * 96;
        if (r < 64) {                     // q (r<32) or k (32..63): hi/lo split
            unsigned short* dst = (r < 32) ? qA : kB;
            int rr   = (r < 32) ? r : (r - 32);
            int part = rr >> 4;           // 0: half1, 1: half2
            int d    = rr & 15;
            float sc = (r < 32) ? SCALE : 1.0f;
            #pragma unroll
            for (int i = 0; i < 4; ++i) {
                float f = acc[oi][i] * sc;
                unsigned u  = __float_as_uint(f);
                unsigned hb = u & 0xFFFF0000u;
                float lo = f - __uint_as_float(hb);
                size_t base = ((size_t)hh * N_TOK + n0 + i) * 64 + part * 32 + d;
                dst[base]      = (unsigned short)(u >> 16);
                dst[base + 16] = (unsigned short)(__float_as_uint(lo) >> 16);
            }
        } else {                          // v -> transposed bf16 RNE
            int d = r - 64;
            #pragma unroll
            for (int i = 0; i < 4; ++i)
                vT[((size_t)hh * 32 + d) * N_TOK + n0 + i] = bf_rne(acc[oi][i]);
        }
    }
}

// ---------------------------------------------------------------------------
// Kernel 2: MFMA flash diff-attention, transposed-S trick: S^T = K.Q^T via
// 16x16x32 bf16 MFMA (A=keys hi|lo, B=queries); the C-layout of S^T (lane
// (quad,m): query m, keys quad*4+i) IS the A-layout of the K=16 PV MFMA
// (mfma_f32_16x16x16bf16_1k) -> exp+pack in-register, ZERO LDS / barriers in
// the K-loop. block = 4 waves; wave w owns keys [w*1024,(w+1)*1024).
// Merge 4 wave-partials via LDS atomics; finalize by wave 0.
// ---------------------------------------------------------------------------
__global__ __launch_bounds__(256, 4) void flash_kernel(
    const unsigned short* __restrict__ qA, const unsigned short* __restrict__ kB,
    const unsigned short* __restrict__ vT, float* __restrict__ out)
{
    __shared__ float Obuf[2][16][32];
    __shared__ float lbuf[2][16];

    const int t    = threadIdx.x;
    const int w    = t >> 6;
    const int lane = t & 63;
    const int m    = lane & 15;
    const int quad = lane >> 4;
    const int h     = blockIdx.x >> 8;
    const int qbase = (blockIdx.x & 255) * 16;

    for (int i = t; i < 1024; i += 256) ((float*)Obuf)[i] = 0.f;
    if (t < 32) ((float*)lbuf)[t] = 0.f;
    __syncthreads();

    // B-operand query fragments (built once per wave)
    const unsigned short* qrec = qA + (size_t)(h * N_TOK + qbase + m) * 64;
    const bf16x8 zz = {0,0,0,0,0,0,0,0};
    bf16x8 Bq1h = *(const bf16x8*)(qrec + (quad & 1) * 8);        // [q1hi|q1hi]
    bf16x8 Bq2h = *(const bf16x8*)(qrec + 32 + (quad & 1) * 8);   // [q2hi|q2hi]
    bf16x8 Bq1l = (quad < 2) ? *(const bf16x8*)(qrec + 16 + quad * 8) : zz; // [q1lo|0]
    bf16x8 Bq2l = (quad < 2) ? *(const bf16x8*)(qrec + 48 + quad * 8) : zz; // [q2lo|0]

    f32x4 O1a = {0,0,0,0}, O1b = {0,0,0,0}, O2a = {0,0,0,0}, O2b = {0,0,0,0};
    float l1 = 0.f, l2 = 0.f;

    const unsigned short* kBh = kB + (size_t)h * N_TOK * 64;
    const unsigned short* vTh = vT + (size_t)h * 32 * N_TOK;

    #pragma unroll 2
    for (int tile = 0; tile < 64; ++tile) {
        const int kb0 = w * 1024 + tile * 16;
        const unsigned short* krec = kBh + (size_t)(kb0 + m) * 64;

        // A-operands: keys (m = key-in-tile), feat = [hi(16)|lo(16)]
        bf16x8 Ak1 = *(const bf16x8*)(krec + quad * 8);
        bf16x8 Ak2 = *(const bf16x8*)(krec + 32 + quad * 8);

        f32x4 s1 = {0,0,0,0};
        s1 = __builtin_amdgcn_mfma_f32_16x16x32_bf16(Ak1, Bq1h, s1, 0, 0, 0);
        s1 = __builtin_amdgcn_mfma_f32_16x16x32_bf16(Ak1, Bq1l, s1, 0, 0, 0);
        f32x4 s2 = {0,0,0,0};
        s2 = __builtin_amdgcn_mfma_f32_16x16x32_bf16(Ak2, Bq2h, s2, 0, 0, 0);
        s2 = __builtin_amdgcn_mfma_f32_16x16x32_bf16(Ak2, Bq2l, s2, 0, 0, 0);

        // exp + truncate-to-bf16 in-register; C-layout == PV A-layout
        bf16x4 aP1, aP2;
        #pragma unroll
        for (int i = 0; i < 4; ++i) {
            float p1 = __expf(s1[i]);
            float p2 = __expf(s2[i]);
            l1 += p1; l2 += p2;
            aP1[i] = (short)(__float_as_uint(p1) >> 16);
            aP2[i] = (short)(__float_as_uint(p2) >> 16);
        }

        // V B-operands (K=16): lane needs V[k=kb0+quad*4+j][dim m / 16+m]
        bf16x4 Vb0 = *(const bf16x4*)(vTh + (size_t)m        * N_TOK + kb0 + quad * 4);
        bf16x4 Vb1 = *(const bf16x4*)(vTh + (size_t)(16 + m) * N_TOK + kb0 + quad * 4);

        O1a = __builtin_amdgcn_mfma_f32_16x16x16bf16_1k(aP1, Vb0, O1a, 0, 0, 0);
        O1b = __builtin_amdgcn_mfma_f32_16x16x16bf16_1k(aP1, Vb1, O1b, 0, 0, 0);
        O2a = __builtin_amdgcn_mfma_f32_16x16x16bf16_1k(aP2, Vb0, O2a, 0, 0, 0);
        O2b = __builtin_amdgcn_mfma_f32_16x16x16bf16_1k(aP2, Vb1, O2b, 0, 0, 0);
    }

    // l: per-lane partial covers keys {quad*4+i}; reduce across quads
    l1 += __shfl_xor(l1, 16, 64); l1 += __shfl_xor(l1, 32, 64);
    l2 += __shfl_xor(l2, 16, 64); l2 += __shfl_xor(l2, 32, 64);
    if (lane < 16) {
        atomicAdd(&lbuf[0][m], l1);
        atomicAdd(&lbuf[1][m], l2);
    }
    #pragma unroll
    for (int i = 0; i < 4; ++i) {
        int r = quad * 4 + i;              // query row
        atomicAdd(&Obuf[0][r][m],      O1a[i]);
        atomicAdd(&Obuf[0][r][16 + m], O1b[i]);
        atomicAdd(&Obuf[1][r][m],      O2a[i]);
        atomicAdd(&Obuf[1][r][16 + m], O2b[i]);
    }
    __syncthreads();

    if (w == 0) {
        #pragma unroll
        for (int i = 0; i < 4; ++i) {
            int r = quad * 4 + i;
            float il1 = 1.0f    / lbuf[0][r];
            float il2 = LAMBDA_ / lbuf[1][r];
            float* op = out + ((size_t)(h * N_TOK + qbase + r)) * 32;
            op[m]      = Obuf[0][r][m]      * il1 - Obuf[1][r][m]      * il2;
            op[16 + m] = Obuf[0][r][16 + m] * il1 - Obuf[1][r][16 + m] * il2;
        }
    }
}

extern "C" void kernel_launch(void* const* d_in, const int* in_sizes, int n_in,
                              void* d_out, int out_size, void* d_ws, size_t ws_size,
                              hipStream_t stream) {
    const float* x = (const float*)d_in[0];   // (1,128,32,32,32)
    const float* w = (const float*)d_in[1];   // (384,128)
    float* out = (float*)d_out;               // [h][n][32] flat (verified R1)

    unsigned short* qA = (unsigned short*)d_ws;               // 2 MB
    unsigned short* kB = qA + (size_t)NH * N_TOK * 64;        // 2 MB
    unsigned short* vT = kB + (size_t)NH * N_TOK * 64;        // 1 MB

    qkv_kernel<<<1024, 128, 0, stream>>>(x, w, qA, kB, vT);
    flash_kernel<<<1024, 256, 0, stream>>>(qA, kB, vT, out);
}

// Round 6
// 156.623 us; speedup vs baseline: 7.6257x; 1.3761x over previous
//
#include <hip/hip_runtime.h>
#include <math.h>

#define N_TOK 4096
#define NH    4

typedef __attribute__((ext_vector_type(8))) short bf16x8;
typedef __attribute__((ext_vector_type(4))) short bf16x4;
typedef __attribute__((ext_vector_type(4))) float f32x4;

static constexpr float SCALE   = 0.17677669529663687f; // 32^-0.5
static constexpr float LAMBDA_ = 0.1f;

__device__ __forceinline__ unsigned short bf_rne(float f) {
    unsigned u = __float_as_uint(f);
    u += 0x7FFF + ((u >> 16) & 1);
    return (unsigned short)(u >> 16);
}

__device__ __forceinline__ void async_copy16(const unsigned short* g, unsigned short* l) {
    __builtin_amdgcn_global_load_lds(
        (const __attribute__((address_space(1))) void*)g,
        (__attribute__((address_space(3))) void*)l, 16, 0, 0);
}

// ---------------------------------------------------------------------------
// Kernel 1: qkv projection + operand packing.
//  qA[h][n][64] bf16: {q1hi(16) q1lo(16) q2hi(16) q2lo(16)}  (scale folded)
//  kB[h][n][64] bf16: {k1hi(16) k1lo(16) k2hi(16) k2lo(16)}
//  vT[h][32][4096] bf16 (transposed, RNE)
// w is staged through LDS in 16-channel chunks with COALESCED global b128
// loads (8 lanes per w-row-line vs row-per-lane before), then read back as
// broadcast-friendly b64. Stride 18 floats: 8B-aligned, 2-way banks (free).
// ---------------------------------------------------------------------------
__global__ __launch_bounds__(128) void qkv_kernel(
    const float* __restrict__ x, const float* __restrict__ w,
    unsigned short* __restrict__ qA, unsigned short* __restrict__ kB,
    unsigned short* __restrict__ vT)
{
    __shared__ __align__(16) float xst[4][132];   // [token][channel]
    __shared__ __align__(16) float w_sh[384][18]; // 16-ch chunk of w, padded
    const int t  = threadIdx.x;
    const int n0 = blockIdx.x * 4;

    #pragma unroll
    for (int i = 0; i < 4; ++i) {
        int n  = n0 + i;
        int nh = n >> 8, nw = (n >> 4) & 15, nz = n & 15;
        xst[i][t] = x[t * 32768 + nh * 2048 + nw * 64 + nz * 2];
    }

    float acc[3][4];
    #pragma unroll
    for (int oi = 0; oi < 3; ++oi)
        #pragma unroll
        for (int i = 0; i < 4; ++i) acc[oi][i] = 0.f;

    for (int chunk = 0; chunk < 8; ++chunk) {
        const int k0 = chunk * 16;
        __syncthreads();                      // prev compute done (and xst ready)
        // stage w[:, k0:k0+16] -> w_sh : 384 rows x 4 float4 = 1536 b128 loads
        #pragma unroll
        for (int i = 0; i < 12; ++i) {
            int idx = t + i * 128;            // 0..1535
            int row = idx >> 2, c4 = idx & 3;
            float4 wv = *(const float4*)(w + (size_t)row * 128 + k0 + c4 * 4);
            *(float2*)&w_sh[row][c4 * 4]     = make_float2(wv.x, wv.y);
            *(float2*)&w_sh[row][c4 * 4 + 2] = make_float2(wv.z, wv.w);
        }
        __syncthreads();
        #pragma unroll
        for (int c4 = 0; c4 < 4; ++c4) {
            float4 xv[4];
            #pragma unroll
            for (int i = 0; i < 4; ++i)
                xv[i] = *(const float4*)&xst[i][k0 + c4 * 4];
            float2 wa0 = *(const float2*)&w_sh[t][c4 * 4];
            float2 wb0 = *(const float2*)&w_sh[t][c4 * 4 + 2];
            float2 wa1 = *(const float2*)&w_sh[t + 128][c4 * 4];
            float2 wb1 = *(const float2*)&w_sh[t + 128][c4 * 4 + 2];
            float2 wa2 = *(const float2*)&w_sh[t + 256][c4 * 4];
            float2 wb2 = *(const float2*)&w_sh[t + 256][c4 * 4 + 2];
            #pragma unroll
            for (int i = 0; i < 4; ++i) {
                acc[0][i] += wa0.x*xv[i].x + wa0.y*xv[i].y + wb0.x*xv[i].z + wb0.y*xv[i].w;
                acc[1][i] += wa1.x*xv[i].x + wa1.y*xv[i].y + wb1.x*xv[i].z + wb1.y*xv[i].w;
                acc[2][i] += wa2.x*xv[i].x + wa2.y*xv[i].y + wb2.x*xv[i].z + wb2.y*xv[i].w;
            }
        }
    }

    #pragma unroll
    for (int oi = 0; oi < 3; ++oi) {
        int o  = t + oi * 128;                // 0..383
        int hh = o / 96;
        int r  = o - hh * 96;
        if (r < 64) {                         // q (r<32) or k (32..63): hi/lo split
            unsigned short* dst = (r < 32) ? qA : kB;
            int rr   = (r < 32) ? r : (r - 32);
            int part = rr >> 4;
            int d    = rr & 15;
            float sc = (r < 32) ? SCALE : 1.0f;
            #pragma unroll
            for (int i = 0; i < 4; ++i) {
                float f = acc[oi][i] * sc;
                unsigned u  = __float_as_uint(f);
                unsigned hb = u & 0xFFFF0000u;
                float lo = f - __uint_as_float(hb);
                size_t base = ((size_t)hh * N_TOK + n0 + i) * 64 + part * 32 + d;
                dst[base]      = (unsigned short)(u >> 16);
                dst[base + 16] = (unsigned short)(__float_as_uint(lo) >> 16);
            }
        } else {                              // v -> transposed bf16 RNE
            int d = r - 64;
            #pragma unroll
            for (int i = 0; i < 4; ++i)
                vT[((size_t)hh * 32 + d) * N_TOK + n0 + i] = bf_rne(acc[oi][i]);
        }
    }
}

// ---------------------------------------------------------------------------
// Kernel 2: MFMA flash diff-attention v3.
// block = 32 queries (2 qtiles) x ALL 4096 keys, 4 waves. Keys processed in
// 64-key tiles staged async (global_load_lds dwordx4, double-buffered); wave
// w takes tile keys [w*16,(w+1)*16) for BOTH qtiles. Granules (16B) are
// XOR-swizzled on the GLOBAL source side (LDS dst must stay base+lane*16),
// so fragment reads are bank-spread without padding.
// In-register S^T->PV layout trick (R5-verified): S^T = K.Q^T via 16x16x32
// (A=K hi|lo, B=Q), C-layout == PV A-layout for 16x16x16bf16_1k.
// Merge 4 wave-partials via LDS atomics; fused finalize.
// ---------------------------------------------------------------------------
__global__ __launch_bounds__(256, 2) void flash_kernel(
    const unsigned short* __restrict__ qA, const unsigned short* __restrict__ kB,
    const unsigned short* __restrict__ vT, float* __restrict__ out)
{
    __shared__ __align__(16) unsigned short kv_sh[2][6144]; // per buf: K 8KB + V 4KB
    __shared__ float Obuf[2][32][32];
    __shared__ float lbuf[2][32];

    const int t    = threadIdx.x;
    const int w    = t >> 6;
    const int lane = t & 63;
    const int m    = lane & 15;
    const int quad = lane >> 4;
    const int h     = blockIdx.x >> 7;
    const int qbase = (blockIdx.x & 127) * 32;

    const unsigned short* kBh = kB + (size_t)h * N_TOK * 64;
    const unsigned short* vTh = vT + (size_t)h * 32 * N_TOK;

    // ---- async stage of one 64-key tile into buf b (768 granules) ----
    auto stage = [&](int tile, int b) {
        const unsigned short* kben = kBh + (size_t)tile * 64 * 64;
        #pragma unroll
        for (int i = 0; i < 3; ++i) {
            int s = i * 256 + t;              // granule slot 0..767
            const unsigned short* src;
            if (s < 512) {                    // K: record ml, granule c
                int ml = s >> 3, p = s & 7, c = p ^ (ml & 7);
                src = kben + ml * 64 + c * 8;
            } else {                          // V: row d, granule c (8 keys)
                int s2 = s - 512;
                int d = s2 >> 3, p = s2 & 7, c = p ^ (d & 7);
                src = vTh + (size_t)d * N_TOK + tile * 64 + c * 8;
            }
            async_copy16(src, &kv_sh[b][s * 8]);
        }
    };

    stage(0, 0);

    for (int i = t; i < 2048; i += 256) ((float*)Obuf)[i] = 0.f;
    if (t < 64) ((float*)lbuf)[t] = 0.f;

    // B-operand query fragments, 2 qtiles (R5-verified construction)
    const unsigned short* qrecA = qA + (size_t)(h * N_TOK + qbase + m) * 64;
    const unsigned short* qrecB = qrecA + 16 * 64;
    const bf16x8 zz = {0,0,0,0,0,0,0,0};
    bf16x8 BA1h = *(const bf16x8*)(qrecA + (quad & 1) * 8);
    bf16x8 BA2h = *(const bf16x8*)(qrecA + 32 + (quad & 1) * 8);
    bf16x8 BA1l = (quad < 2) ? *(const bf16x8*)(qrecA + 16 + quad * 8) : zz;
    bf16x8 BA2l = (quad < 2) ? *(const bf16x8*)(qrecA + 48 + quad * 8) : zz;
    bf16x8 BB1h = *(const bf16x8*)(qrecB + (quad & 1) * 8);
    bf16x8 BB2h = *(const bf16x8*)(qrecB + 32 + (quad & 1) * 8);
    bf16x8 BB1l = (quad < 2) ? *(const bf16x8*)(qrecB + 16 + quad * 8) : zz;
    bf16x8 BB2l = (quad < 2) ? *(const bf16x8*)(qrecB + 48 + quad * 8) : zz;

    f32x4 OA1a = {0,0,0,0}, OA1b = {0,0,0,0}, OA2a = {0,0,0,0}, OA2b = {0,0,0,0};
    f32x4 OB1a = {0,0,0,0}, OB1b = {0,0,0,0}, OB2a = {0,0,0,0}, OB2b = {0,0,0,0};
    float l1a = 0.f, l2a = 0.f, l1b = 0.f, l2b = 0.f;

    // fragment LDS addresses (swizzled granules)
    const int ml  = w * 16 + m;               // local key record
    const int sw  = ml & 7;
    const int ak1_off = ml * 64 + ((quad)     ^ sw) * 8;
    const int ak2_off = ml * 64 + ((4 + quad) ^ sw) * 8;
    const int vg  = 2 * w + (quad >> 1);      // V granule (pre-swizzle)
    const int vh  = (quad & 1) * 4;
    const int v0_off = 4096 + m        * 64 + (vg ^ (m & 7))        * 8 + vh;
    const int v1_off = 4096 + (16 + m) * 64 + (vg ^ ((16 + m) & 7)) * 8 + vh;

    for (int tile = 0; tile < 64; ++tile) {
        const int b = tile & 1;
        __syncthreads();                      // drains stage of buf b
        if (tile + 1 < 64) stage(tile + 1, b ^ 1);

        const unsigned short* buf = kv_sh[b];
        bf16x8 Ak1 = *(const bf16x8*)(buf + ak1_off);
        bf16x8 Ak2 = *(const bf16x8*)(buf + ak2_off);

        f32x4 sa1 = {0,0,0,0}, sa2 = {0,0,0,0}, sb1 = {0,0,0,0}, sb2 = {0,0,0,0};
        sa1 = __builtin_amdgcn_mfma_f32_16x16x32_bf16(Ak1, BA1h, sa1, 0, 0, 0);
        sa1 = __builtin_amdgcn_mfma_f32_16x16x32_bf16(Ak1, BA1l, sa1, 0, 0, 0);
        sa2 = __builtin_amdgcn_mfma_f32_16x16x32_bf16(Ak2, BA2h, sa2, 0, 0, 0);
        sa2 = __builtin_amdgcn_mfma_f32_16x16x32_bf16(Ak2, BA2l, sa2, 0, 0, 0);
        sb1 = __builtin_amdgcn_mfma_f32_16x16x32_bf16(Ak1, BB1h, sb1, 0, 0, 0);
        sb1 = __builtin_amdgcn_mfma_f32_16x16x32_bf16(Ak1, BB1l, sb1, 0, 0, 0);
        sb2 = __builtin_amdgcn_mfma_f32_16x16x32_bf16(Ak2, BB2h, sb2, 0, 0, 0);
        sb2 = __builtin_amdgcn_mfma_f32_16x16x32_bf16(Ak2, BB2l, sb2, 0, 0, 0);

        bf16x4 aPA1, aPA2, aPB1, aPB2;
        #pragma unroll
        for (int i = 0; i < 4; ++i) {
            float pa1 = __expf(sa1[i]), pa2 = __expf(sa2[i]);
            float pb1 = __expf(sb1[i]), pb2 = __expf(sb2[i]);
            l1a += pa1; l2a += pa2; l1b += pb1; l2b += pb2;
            aPA1[i] = (short)(__float_as_uint(pa1) >> 16);
            aPA2[i] = (short)(__float_as_uint(pa2) >> 16);
            aPB1[i] = (short)(__float_as_uint(pb1) >> 16);
            aPB2[i] = (short)(__float_as_uint(pb2) >> 16);
        }

        bf16x4 Vb0 = *(const bf16x4*)(buf + v0_off);
        bf16x4 Vb1 = *(const bf16x4*)(buf + v1_off);

        OA1a = __builtin_amdgcn_mfma_f32_16x16x16bf16_1k(aPA1, Vb0, OA1a, 0, 0, 0);
        OA1b = __builtin_amdgcn_mfma_f32_16x16x16bf16_1k(aPA1, Vb1, OA1b, 0, 0, 0);
        OA2a = __builtin_amdgcn_mfma_f32_16x16x16bf16_1k(aPA2, Vb0, OA2a, 0, 0, 0);
        OA2b = __builtin_amdgcn_mfma_f32_16x16x16bf16_1k(aPA2, Vb1, OA2b, 0, 0, 0);
        OB1a = __builtin_amdgcn_mfma_f32_16x16x16bf16_1k(aPB1, Vb0, OB1a, 0, 0, 0);
        OB1b = __builtin_amdgcn_mfma_f32_16x16x16bf16_1k(aPB1, Vb1, OB1b, 0, 0, 0);
        OB2a = __builtin_amdgcn_mfma_f32_16x16x16bf16_1k(aPB2, Vb0, OB2a, 0, 0, 0);
        OB2b = __builtin_amdgcn_mfma_f32_16x16x16bf16_1k(aPB2, Vb1, OB2b, 0, 0, 0);
    }

    // reduce l across quads (each lane covers 4 keys of query m / 16+m)
    l1a += __shfl_xor(l1a, 16, 64); l1a += __shfl_xor(l1a, 32, 64);
    l2a += __shfl_xor(l2a, 16, 64); l2a += __shfl_xor(l2a, 32, 64);
    l1b += __shfl_xor(l1b, 16, 64); l1b += __shfl_xor(l1b, 32, 64);
    l2b += __shfl_xor(l2b, 16, 64); l2b += __shfl_xor(l2b, 32, 64);
    if (lane < 16) {
        atomicAdd(&lbuf[0][m], l1a);      atomicAdd(&lbuf[1][m], l2a);
        atomicAdd(&lbuf[0][16 + m], l1b); atomicAdd(&lbuf[1][16 + m], l2b);
    }
    #pragma unroll
    for (int i = 0; i < 4; ++i) {
        int r = quad * 4 + i;                 // query row within qtile
        atomicAdd(&Obuf[0][r][m],      OA1a[i]);
        atomicAdd(&Obuf[0][r][16 + m], OA1b[i]);
        atomicAdd(&Obuf[1][r][m],      OA2a[i]);
        atomicAdd(&Obuf[1][r][16 + m], OA2b[i]);
        atomicAdd(&Obuf[0][16 + r][m],      OB1a[i]);
        atomicAdd(&Obuf[0][16 + r][16 + m], OB1b[i]);
        atomicAdd(&Obuf[1][16 + r][m],      OB2a[i]);
        atomicAdd(&Obuf[1][16 + r][16 + m], OB2b[i]);
    }
    __syncthreads();

    for (int i = t; i < 32 * 32; i += 256) {
        int r = i >> 5, d = i & 31;
        float il1 = 1.0f    / lbuf[0][r];
        float il2 = LAMBDA_ / lbuf[1][r];
        out[(size_t)(h * N_TOK + qbase) * 32 + i] =
            Obuf[0][r][d] * il1 - Obuf[1][r][d] * il2;
    }
}

extern "C" void kernel_launch(void* const* d_in, const int* in_sizes, int n_in,
                              void* d_out, int out_size, void* d_ws, size_t ws_size,
                              hipStream_t stream) {
    const float* x = (const float*)d_in[0];   // (1,128,32,32,32)
    const float* w = (const float*)d_in[1];   // (384,128)
    float* out = (float*)d_out;               // [h][n][32] flat (verified R1)

    unsigned short* qA = (unsigned short*)d_ws;               // 2 MB
    unsigned short* kB = qA + (size_t)NH * N_TOK * 64;        // 2 MB
    unsigned short* vT = kB + (size_t)NH * N_TOK * 64;        // 1 MB

    qkv_kernel<<<1024, 128, 0, stream>>>(x, w, qA, kB, vT);
    flash_kernel<<<512, 256, 0, stream>>>(qA, kB, vT, out);
}